// Round 7
// baseline (101.311 us; speedup 1.0000x reference)
//
#include <hip/hip_runtime.h>
#include <hip/hip_bf16.h>

// NetVLAD MI355X v7: eliminate partial buffer + reduce kernel.
// prep:  centers -> swizzled bf16 hi/lo image + c2[b][k]; zero vlad/ssumG/sqG/ctr.
// main:  r3/v5-verified MFMA pipeline; epilogue atomicAdds vac into vlad (1 MB)
//        and block ssum into ssumG[b][k] (f32 device-scope atomics, native at L2).
// finish: a = vlad - ssum*c (exact f32 centers), global sq via atomic + arrive-
//        counter spin barrier (256 blocks <= 256 CUs, co-resident), scale -> out.
// Phase 1: scores = 2*F.C^T - |c|^2, split-bf16 MFMA (3 terms) [verified r2-r6]
// Phase 2: vlad_pos = simT x F_T bf16 MFMA, chunk-XOR swizzles [verified r3-r6]

#define NB    32
#define SPLIT 16

typedef short short8 __attribute__((ext_vector_type(8)));
typedef float f32x4  __attribute__((ext_vector_type(4)));

__device__ __forceinline__ float bf2f(unsigned short u) {
    return __uint_as_float(((unsigned)u) << 16);
}
__device__ __forceinline__ unsigned short f2bf(float f) {
    __hip_bfloat16 h = __float2bfloat16(f);   // RNE
    unsigned short u;
    __builtin_memcpy(&u, &h, 2);
    return u;
}
__device__ __forceinline__ int swz3(int x) { return (x ^ (x >> 3)) & 7; }

// ---- prep: center image + c2 + zero-init of accumulators ----
// cws per batch: 4096 ushort4 (hi [0,2048), lo [2048,4096)); slot k*32+(d4^((k&7)<<1))
__global__ __launch_bounds__(256)
void netvlad_prep(const float* __restrict__ cent,
                  ushort4* __restrict__ cws,
                  float* __restrict__ c2G,
                  float* __restrict__ vlad,
                  float* __restrict__ ssumG,
                  float* __restrict__ sqG,
                  unsigned int* __restrict__ ctr) {
    const int tid = threadIdx.x;
    const int bi  = blockIdx.x;      // 256 blocks = 32 b x 8 k-groups
    const int b   = bi >> 3;
    const int kg  = bi & 7;
    const int kk  = tid >> 5;        // 0..7
    const int d4  = tid & 31;
    const int k   = kg * 8 + kk;
    float4 v = ((const float4*)cent)[(size_t)b * 2048 + k * 32 + d4];
    ushort4 h, l;
    h.x = f2bf(v.x); l.x = f2bf(v.x - bf2f(h.x));
    h.y = f2bf(v.y); l.y = f2bf(v.y - bf2f(h.y));
    h.z = f2bf(v.z); l.z = f2bf(v.z - bf2f(h.z));
    h.w = f2bf(v.w); l.w = f2bf(v.w - bf2f(h.w));
    int slot = k * 32 + (d4 ^ ((k & 7) << 1));
    cws[(size_t)b * 4096 + slot]        = h;
    cws[(size_t)b * 4096 + 2048 + slot] = l;
    float a = v.x * v.x + v.y * v.y + v.z * v.z + v.w * v.w;
    a += __shfl_xor(a, 1);
    a += __shfl_xor(a, 2);
    a += __shfl_xor(a, 4);
    a += __shfl_xor(a, 8);
    a += __shfl_xor(a, 16);
    if (d4 == 0) c2G[b * 64 + k] = a;

    // zero-init accumulators (ws is poisoned 0xAA before every call)
    ((float4*)vlad)[bi * 256 + tid] = make_float4(0.f, 0.f, 0.f, 0.f);  // 1 MB
    if (bi < 8) ssumG[bi * 256 + tid] = 0.f;                            // 2048 f
    if (bi == 0 && tid == 0) { sqG[0] = 0.f; ctr[0] = 0u; }
}

// LDS map (58,368 B -> 2 blocks/CU):
// [    0,16384) centHi bf16[64][128], ushort4 slot: k*32 + (d4 ^ ((k&7)<<1))
// [16384,32768) centLo same layout
// [32768,49152) F_T  bf16[128][64], elem: d*64 + (((p>>3) ^ swz3(d))<<3) + (p&7)
// [49152,57344) simT bf16[64][64],  elem: k*64 + (((p>>3) ^ swz3(k))<<3) + (p&7)
// [57344,58368) ssumW f32[4][64]
__global__ __launch_bounds__(256, 2)
void netvlad_main(const float* __restrict__ feat,
                  const ushort4* __restrict__ cws,
                  const float* __restrict__ c2G,
                  float* __restrict__ vlad,
                  float* __restrict__ ssumG)
{
    __shared__ __align__(16) char smem[58368];
    unsigned short* FT    = (unsigned short*)(smem + 32768);
    unsigned short* ST    = (unsigned short*)(smem + 49152);
    float*          ssumW = (float*)(smem + 57344);

    const int tid = threadIdx.x;
    const int bs  = blockIdx.x;
    const int b   = bs >> 4;
    const int n0  = (bs & 15) * 64;

    // ---- stage pre-swizzled center image: pure 16B copies ----
    const uint4* csrc = (const uint4*)(cws + (size_t)b * 4096);
    #pragma unroll
    for (int it = 0; it < 8; ++it)
        ((uint4*)smem)[it * 256 + tid] = csrc[it * 256 + tid];

    const float4* feat4 = (const float4*)feat + ((size_t)b * 1024 + n0) * 32;

    const int w    = tid >> 6;
    const int lane = tid & 63;
    const int lr   = lane & 15;
    const int lg   = lane >> 4;
    const int prow = 16 * w + lr;     // pixel row 0..63

    // ---- c2 from global (L2-hit) ----
    float c2r[4];
    #pragma unroll
    for (int nt = 0; nt < 4; ++nt) c2r[nt] = c2G[b * 64 + nt * 16 + lr];

    // ---- A-frags: global -> regs, split bf16 hi/lo; scatter FT (hi) ----
    short8 ah[4], al[4];
    #pragma unroll
    for (int kt = 0; kt < 4; ++kt) {
        float4 fa = feat4[prow * 32 + kt * 8 + 2 * lg + 0];
        float4 fb = feat4[prow * 32 + kt * 8 + 2 * lg + 1];
        float fv[8] = { fa.x, fa.y, fa.z, fa.w, fb.x, fb.y, fb.z, fb.w };
        #pragma unroll
        for (int j = 0; j < 8; ++j) {
            unsigned short h = f2bf(fv[j]);
            ah[kt][j] = (short)h;
            al[kt][j] = (short)f2bf(fv[j] - bf2f(h));
            int d = kt * 32 + 8 * lg + j;
            FT[d * 64 + ((((prow >> 3) ^ swz3(d))) << 3) + (prow & 7)] = h;
        }
    }
    __syncthreads();

    // ---- phase 1: scores via split-bf16 MFMA ----
    f32x4 acc[4];
    #pragma unroll
    for (int nt = 0; nt < 4; ++nt) acc[nt] = (f32x4){0.f, 0.f, 0.f, 0.f};
    #pragma unroll
    for (int kt = 0; kt < 4; ++kt) {
        #pragma unroll
        for (int nt = 0; nt < 4; ++nt) {
            int c  = nt * 16 + lr;
            int ch = c * 16 + ((kt * 4 + lg) ^ (c & 7));
            short8 bh = *(const short8*)(smem + ch * 16);
            short8 bl = *(const short8*)(smem + 16384 + ch * 16);
            acc[nt] = __builtin_amdgcn_mfma_f32_16x16x32_bf16(ah[kt], bh, acc[nt], 0, 0, 0);
            acc[nt] = __builtin_amdgcn_mfma_f32_16x16x32_bf16(ah[kt], bl, acc[nt], 0, 0, 0);
            acc[nt] = __builtin_amdgcn_mfma_f32_16x16x32_bf16(al[kt], bh, acc[nt], 0, 0, 0);
        }
    }

    // ---- softmax; write simT bf16; ssum partials ----
    float ssp[4] = {0.f, 0.f, 0.f, 0.f};
    #pragma unroll
    for (int r = 0; r < 4; ++r) {
        float s[4];
        #pragma unroll
        for (int nt = 0; nt < 4; ++nt) s[nt] = 2.f * acc[nt][r] - c2r[nt];
        float m = fmaxf(fmaxf(s[0], s[1]), fmaxf(s[2], s[3]));
        #pragma unroll
        for (int o = 8; o >= 1; o >>= 1) m = fmaxf(m, __shfl_xor(m, o));
        float e[4], t = 0.f;
        #pragma unroll
        for (int nt = 0; nt < 4; ++nt) { e[nt] = __expf(s[nt] - m); t += e[nt]; }
        #pragma unroll
        for (int o = 8; o >= 1; o >>= 1) t += __shfl_xor(t, o);
        float inv = __builtin_amdgcn_rcpf(t);
        int p = 16 * w + 4 * lg + r;
        #pragma unroll
        for (int nt = 0; nt < 4; ++nt) {
            int k = nt * 16 + lr;
            float val = e[nt] * inv;
            ssp[nt] += val;
            ST[k * 64 + ((((p >> 3) ^ swz3(k))) << 3) + (p & 7)] = f2bf(val);
        }
    }
    #pragma unroll
    for (int nt = 0; nt < 4; ++nt) {
        float v = ssp[nt];
        v += __shfl_xor(v, 16);
        v += __shfl_xor(v, 32);
        if (lg == 0) ssumW[w * 64 + nt * 16 + lr] = v;
    }
    __syncthreads();

    // ---- block ssum -> global accumulator (64 f32 atomics/block) ----
    if (tid < 64) {
        float s = ssumW[tid] + ssumW[64 + tid] + ssumW[128 + tid] + ssumW[192 + tid];
        atomicAdd(&ssumG[b * 64 + tid], s);
    }

    // ---- phase 2: vlad_pos = simT x F_T via MFMA; wave w owns k-tile w ----
    f32x4 vac[8];
    #pragma unroll
    for (int dt = 0; dt < 8; ++dt) vac[dt] = (f32x4){0.f, 0.f, 0.f, 0.f};
    const int krow = 16 * w + lr;
    #pragma unroll
    for (int ks = 0; ks < 2; ++ks) {
        int cA = (ks * 4 + lg) ^ swz3(krow);
        short8 af = *(const short8*)(ST + krow * 64 + (cA << 3));
        #pragma unroll
        for (int dt = 0; dt < 8; ++dt) {
            int d  = dt * 16 + lr;
            int cB = (ks * 4 + lg) ^ swz3(d);
            short8 bf = *(const short8*)(FT + d * 64 + (cB << 3));
            vac[dt] = __builtin_amdgcn_mfma_f32_16x16x32_bf16(af, bf, vac[dt], 0, 0, 0);
        }
    }

    // ---- epilogue: accumulate straight into vlad[b] (f32 atomics, L2-native) ----
    float* vb = vlad + (size_t)b * 8192;
    #pragma unroll
    for (int r = 0; r < 4; ++r) {
        int k = 16 * w + 4 * lg + r;
        #pragma unroll
        for (int dt = 0; dt < 8; ++dt)
            atomicAdd(&vb[k * 128 + dt * 16 + lr], vac[dt][r]);
    }
}

// Fused (vlad - ssum*c) + global sq + spin barrier + scale -> out.
// 256 blocks x 256 threads, no LDS pressure -> co-resident on 256 CUs.
__global__ __launch_bounds__(256)
void netvlad_finish(const float* __restrict__ vlad,
                    const float* __restrict__ cent,
                    const float* __restrict__ ssumG,
                    float* __restrict__ sqG,
                    unsigned int* __restrict__ ctr,
                    float* __restrict__ out) {
    __shared__ float wsum[4];
    const int tid = threadIdx.x;
    int idx = blockIdx.x * 256 + tid;   // float4 id over (b, k, d4), 65536 total
    int b   = idx >> 11;
    int rem = idx & 2047;
    int k   = rem >> 5;
    float4 a  = ((const float4*)vlad)[idx];
    float  ss = ssumG[b * 64 + k];
    float4 c4 = ((const float4*)cent)[b * 2048 + rem];
    a.x -= ss * c4.x; a.y -= ss * c4.y; a.z -= ss * c4.z; a.w -= ss * c4.w;

    float sq = a.x * a.x + a.y * a.y + a.z * a.z + a.w * a.w;
    #pragma unroll
    for (int o = 32; o >= 1; o >>= 1) sq += __shfl_xor(sq, o);
    if ((tid & 63) == 0) wsum[tid >> 6] = sq;
    __syncthreads();
    if (tid == 0) {
        atomicAdd(sqG, wsum[0] + wsum[1] + wsum[2] + wsum[3]);
        __threadfence();
        atomicAdd(ctr, 1u);
        while (__hip_atomic_load(ctr, __ATOMIC_ACQUIRE, __HIP_MEMORY_SCOPE_AGENT) < 256u)
            __builtin_amdgcn_s_sleep(8);
    }
    __syncthreads();

    float t = __hip_atomic_load(sqG, __ATOMIC_RELAXED, __HIP_MEMORY_SCOPE_AGENT);
    float inv = __builtin_amdgcn_rcpf(sqrtf(fmaxf(t, 1e-12f)));
    ((float4*)out)[idx] = make_float4(a.x * inv, a.y * inv, a.z * inv, a.w * inv);
}

extern "C" void kernel_launch(void* const* d_in, const int* in_sizes, int n_in,
                              void* d_out, int out_size, void* d_ws, size_t ws_size,
                              hipStream_t stream) {
    const float* feat = (const float*)d_in[0];   // (32,32,32,128)
    const float* cent = (const float*)d_in[1];   // (32,64,128)
    float* out = (float*)d_out;                  // (32,8192)

    char* ws = (char*)d_ws;
    const size_t cws_bytes  = (size_t)NB * 4096 * sizeof(ushort4);   // 1 MB
    const size_t c2_bytes   = (size_t)NB * 64 * sizeof(float);       // 8 KB
    const size_t vlad_bytes = (size_t)NB * 64 * 128 * sizeof(float); // 1 MB
    const size_t ssum_bytes = (size_t)NB * 64 * sizeof(float);       // 8 KB

    ushort4*      cwsp  = (ushort4*)ws;
    float*        c2G   = (float*)(ws + cws_bytes);
    float*        vlad  = (float*)(ws + cws_bytes + c2_bytes);
    float*        ssumG = (float*)(ws + cws_bytes + c2_bytes + vlad_bytes);
    float*        sqG   = (float*)(ws + cws_bytes + c2_bytes + vlad_bytes + ssum_bytes);
    unsigned int* ctr   = (unsigned int*)(ws + cws_bytes + c2_bytes + vlad_bytes + ssum_bytes + 256);

    netvlad_prep  <<<256, 256, 0, stream>>>(cent, cwsp, c2G, vlad, ssumG, sqG, ctr);
    netvlad_main  <<<NB * SPLIT, 256, 0, stream>>>(feat, cwsp, c2G, vlad, ssumG);
    netvlad_finish<<<256, 256, 0, stream>>>(vlad, cent, ssumG, sqG, ctr, out);
}

// Round 9
// 91.430 us; speedup vs baseline: 1.1081x; 1.1081x over previous
//
#include <hip/hip_runtime.h>
#include <hip/hip_bf16.h>

// NetVLAD MI355X v8 (resubmit — r8 bench was a broker timeout, never measured):
// r3 topology (store partial, no atomics) with
//  (a) SPLIT=8 + in-kernel 2-iter loop (vac/ssum accumulate in regs) -> partial 8 MB
//  (b) reduce+norm fused into finish via v7-verified spin barrier.
// Geometry unchanged from best (256 thr, 58.4 KB LDS, 2 blocks/CU).
// Phase 1: scores = 2*F.C^T - |c|^2, split-bf16 MFMA (3 terms) [verified r2-r7]
// Phase 2: vlad_pos = simT x F_T bf16 MFMA, chunk-XOR swizzles [verified r3-r7]

#define NB    32
#define SPLIT 8

typedef short short8 __attribute__((ext_vector_type(8)));
typedef float f32x4  __attribute__((ext_vector_type(4)));

__device__ __forceinline__ float bf2f(unsigned short u) {
    return __uint_as_float(((unsigned)u) << 16);
}
__device__ __forceinline__ unsigned short f2bf(float f) {
    __hip_bfloat16 h = __float2bfloat16(f);   // RNE
    unsigned short u;
    __builtin_memcpy(&u, &h, 2);
    return u;
}
__device__ __forceinline__ int swz3(int x) { return (x ^ (x >> 3)) & 7; }

// ---- prep: center image + c2 + init of sqG/ctr ----
// cws per batch: 4096 ushort4 (hi [0,2048), lo [2048,4096)); slot k*32+(d4^((k&7)<<1))
__global__ __launch_bounds__(256)
void netvlad_prep(const float* __restrict__ cent,
                  ushort4* __restrict__ cws,
                  float* __restrict__ c2G,
                  float* __restrict__ sqG,
                  unsigned int* __restrict__ ctr) {
    const int tid = threadIdx.x;
    const int bi  = blockIdx.x;      // 256 blocks = 32 b x 8 k-groups
    const int b   = bi >> 3;
    const int kg  = bi & 7;
    const int kk  = tid >> 5;        // 0..7
    const int d4  = tid & 31;
    const int k   = kg * 8 + kk;
    float4 v = ((const float4*)cent)[(size_t)b * 2048 + k * 32 + d4];
    ushort4 h, l;
    h.x = f2bf(v.x); l.x = f2bf(v.x - bf2f(h.x));
    h.y = f2bf(v.y); l.y = f2bf(v.y - bf2f(h.y));
    h.z = f2bf(v.z); l.z = f2bf(v.z - bf2f(h.z));
    h.w = f2bf(v.w); l.w = f2bf(v.w - bf2f(h.w));
    int slot = k * 32 + (d4 ^ ((k & 7) << 1));
    cws[(size_t)b * 4096 + slot]        = h;
    cws[(size_t)b * 4096 + 2048 + slot] = l;
    float a = v.x * v.x + v.y * v.y + v.z * v.z + v.w * v.w;
    a += __shfl_xor(a, 1);
    a += __shfl_xor(a, 2);
    a += __shfl_xor(a, 4);
    a += __shfl_xor(a, 8);
    a += __shfl_xor(a, 16);
    if (d4 == 0) c2G[b * 64 + k] = a;
    if (bi == 0 && tid == 0) { sqG[0] = 0.f; ctr[0] = 0u; }
}

// LDS map (58,368 B -> 2 blocks/CU):
// [    0,16384) centHi bf16[64][128], ushort4 slot: k*32 + (d4 ^ ((k&7)<<1))
// [16384,32768) centLo same layout
// [32768,49152) F_T  bf16[128][64], elem: d*64 + (((p>>3) ^ swz3(d))<<3) + (p&7)
// [49152,57344) simT bf16[64][64],  elem: k*64 + (((p>>3) ^ swz3(k))<<3) + (p&7)
// [57344,58368) ssumW f32[4][64]
__global__ __launch_bounds__(256, 2)
void netvlad_main(const float* __restrict__ feat,
                  const ushort4* __restrict__ cws,
                  const float* __restrict__ c2G,
                  float* __restrict__ partial,
                  float* __restrict__ ssumG)
{
    __shared__ __align__(16) char smem[58368];
    unsigned short* FT    = (unsigned short*)(smem + 32768);
    unsigned short* ST    = (unsigned short*)(smem + 49152);
    float*          ssumW = (float*)(smem + 57344);

    const int tid = threadIdx.x;
    const int bs  = blockIdx.x;          // 0..255
    const int b   = bs >> 3;
    const int n0  = (bs & 7) * 128;      // 128 pixels per block, 2 iters of 64

    // ---- stage pre-swizzled center image: pure 16B copies ----
    const uint4* csrc = (const uint4*)(cws + (size_t)b * 4096);
    #pragma unroll
    for (int it = 0; it < 8; ++it)
        ((uint4*)smem)[it * 256 + tid] = csrc[it * 256 + tid];

    const int w    = tid >> 6;
    const int lane = tid & 63;
    const int lr   = lane & 15;
    const int lg   = lane >> 4;
    const int prow = 16 * w + lr;     // pixel row within 64-chunk

    // ---- c2 from global (L2-hit) ----
    float c2r[4];
    #pragma unroll
    for (int nt = 0; nt < 4; ++nt) c2r[nt] = c2G[b * 64 + nt * 16 + lr];

    f32x4 vac[8];
    #pragma unroll
    for (int dt = 0; dt < 8; ++dt) vac[dt] = (f32x4){0.f, 0.f, 0.f, 0.f};
    float ssp[4] = {0.f, 0.f, 0.f, 0.f};

    for (int iter = 0; iter < 2; ++iter) {
        const float4* feat4 = (const float4*)feat + ((size_t)b * 1024 + n0 + iter * 64) * 32;

        // ---- A-frags: global -> regs, split bf16 hi/lo; scatter FT (hi) ----
        short8 ah[4], al[4];
        #pragma unroll
        for (int kt = 0; kt < 4; ++kt) {
            float4 fa = feat4[prow * 32 + kt * 8 + 2 * lg + 0];
            float4 fb = feat4[prow * 32 + kt * 8 + 2 * lg + 1];
            float fv[8] = { fa.x, fa.y, fa.z, fa.w, fb.x, fb.y, fb.z, fb.w };
            #pragma unroll
            for (int j = 0; j < 8; ++j) {
                unsigned short h = f2bf(fv[j]);
                ah[kt][j] = (short)h;
                al[kt][j] = (short)f2bf(fv[j] - bf2f(h));
                int d = kt * 32 + 8 * lg + j;
                FT[d * 64 + ((((prow >> 3) ^ swz3(d))) << 3) + (prow & 7)] = h;
            }
        }
        __syncthreads();   // FT (and iter0: centers) visible

        // ---- phase 1: scores via split-bf16 MFMA ----
        f32x4 acc[4];
        #pragma unroll
        for (int nt = 0; nt < 4; ++nt) acc[nt] = (f32x4){0.f, 0.f, 0.f, 0.f};
        #pragma unroll
        for (int kt = 0; kt < 4; ++kt) {
            #pragma unroll
            for (int nt = 0; nt < 4; ++nt) {
                int c  = nt * 16 + lr;
                int ch = c * 16 + ((kt * 4 + lg) ^ (c & 7));
                short8 bh = *(const short8*)(smem + ch * 16);
                short8 bl = *(const short8*)(smem + 16384 + ch * 16);
                acc[nt] = __builtin_amdgcn_mfma_f32_16x16x32_bf16(ah[kt], bh, acc[nt], 0, 0, 0);
                acc[nt] = __builtin_amdgcn_mfma_f32_16x16x32_bf16(ah[kt], bl, acc[nt], 0, 0, 0);
                acc[nt] = __builtin_amdgcn_mfma_f32_16x16x32_bf16(al[kt], bh, acc[nt], 0, 0, 0);
            }
        }

        // ---- softmax; write simT bf16; ssp accumulates across iters ----
        #pragma unroll
        for (int r = 0; r < 4; ++r) {
            float s[4];
            #pragma unroll
            for (int nt = 0; nt < 4; ++nt) s[nt] = 2.f * acc[nt][r] - c2r[nt];
            float m = fmaxf(fmaxf(s[0], s[1]), fmaxf(s[2], s[3]));
            #pragma unroll
            for (int o = 8; o >= 1; o >>= 1) m = fmaxf(m, __shfl_xor(m, o));
            float e[4], t = 0.f;
            #pragma unroll
            for (int nt = 0; nt < 4; ++nt) { e[nt] = __expf(s[nt] - m); t += e[nt]; }
            #pragma unroll
            for (int o = 8; o >= 1; o >>= 1) t += __shfl_xor(t, o);
            float inv = __builtin_amdgcn_rcpf(t);
            int p = 16 * w + 4 * lg + r;
            #pragma unroll
            for (int nt = 0; nt < 4; ++nt) {
                int k = nt * 16 + lr;
                float val = e[nt] * inv;
                ssp[nt] += val;
                ST[k * 64 + ((((p >> 3) ^ swz3(k))) << 3) + (p & 7)] = f2bf(val);
            }
        }
        __syncthreads();   // ST visible

        // ---- phase 2: vlad_pos accumulates into vac across iters ----
        const int krow = 16 * w + lr;
        #pragma unroll
        for (int ks = 0; ks < 2; ++ks) {
            int cA = (ks * 4 + lg) ^ swz3(krow);
            short8 af = *(const short8*)(ST + krow * 64 + (cA << 3));
            #pragma unroll
            for (int dt = 0; dt < 8; ++dt) {
                int d  = dt * 16 + lr;
                int cB = (ks * 4 + lg) ^ swz3(d);
                short8 bf = *(const short8*)(FT + d * 64 + (cB << 3));
                vac[dt] = __builtin_amdgcn_mfma_f32_16x16x32_bf16(af, bf, vac[dt], 0, 0, 0);
            }
        }
        __syncthreads();   // ph2 reads done before next iter overwrites FT/ST
    }

    // ---- block ssum reduce -> ssumG[bs] ----
    #pragma unroll
    for (int nt = 0; nt < 4; ++nt) {
        float v = ssp[nt];
        v += __shfl_xor(v, 16);
        v += __shfl_xor(v, 32);
        if (lg == 0) ssumW[w * 64 + nt * 16 + lr] = v;
    }
    __syncthreads();
    if (tid < 64)
        ssumG[bs * 64 + tid] = ssumW[tid] + ssumW[64 + tid] + ssumW[128 + tid] + ssumW[192 + tid];

    // ---- write vlad_pos partial (8 MB total) ----
    float* outp = partial + (size_t)bs * 8192;
    #pragma unroll
    for (int r = 0; r < 4; ++r) {
        int k = 16 * w + 4 * lg + r;
        #pragma unroll
        for (int dt = 0; dt < 8; ++dt)
            outp[k * 128 + dt * 16 + lr] = vac[dt][r];
    }
}

// Fused reduce(8 splits) + (-ssum*c) + global sq + spin barrier + scale -> out.
// 256 blocks x 256 threads, tiny LDS -> co-resident on 256 CUs [verified v7].
__global__ __launch_bounds__(256)
void netvlad_finish(const float* __restrict__ partial,
                    const float* __restrict__ cent,
                    const float* __restrict__ ssumG,
                    float* __restrict__ sqG,
                    unsigned int* __restrict__ ctr,
                    float* __restrict__ out) {
    __shared__ float wsum[4];
    const int tid = threadIdx.x;
    int idx = blockIdx.x * 256 + tid;   // float4 id over (b, k, d4), 65536 total
    int b   = idx >> 11;
    int rem = idx & 2047;
    int k   = rem >> 5;
    const float4* p4 = (const float4*)partial;
    float4 a = make_float4(0.f, 0.f, 0.f, 0.f);
    float  ss = 0.f;
    #pragma unroll
    for (int s = 0; s < SPLIT; ++s) {
        float4 v = p4[((size_t)(b * SPLIT + s)) * 2048 + rem];
        a.x += v.x; a.y += v.y; a.z += v.z; a.w += v.w;
        ss += ssumG[(b * SPLIT + s) * 64 + k];
    }
    float4 c4 = ((const float4*)cent)[b * 2048 + rem];
    a.x -= ss * c4.x; a.y -= ss * c4.y; a.z -= ss * c4.z; a.w -= ss * c4.w;

    float sq = a.x * a.x + a.y * a.y + a.z * a.z + a.w * a.w;
    #pragma unroll
    for (int o = 32; o >= 1; o >>= 1) sq += __shfl_xor(sq, o);
    if ((tid & 63) == 0) wsum[tid >> 6] = sq;
    __syncthreads();
    if (tid == 0) {
        atomicAdd(sqG, wsum[0] + wsum[1] + wsum[2] + wsum[3]);
        __threadfence();
        atomicAdd(ctr, 1u);
        while (__hip_atomic_load(ctr, __ATOMIC_ACQUIRE, __HIP_MEMORY_SCOPE_AGENT) < 256u)
            __builtin_amdgcn_s_sleep(8);
    }
    __syncthreads();

    float t = __hip_atomic_load(sqG, __ATOMIC_RELAXED, __HIP_MEMORY_SCOPE_AGENT);
    float inv = __builtin_amdgcn_rcpf(sqrtf(fmaxf(t, 1e-12f)));
    ((float4*)out)[idx] = make_float4(a.x * inv, a.y * inv, a.z * inv, a.w * inv);
}

extern "C" void kernel_launch(void* const* d_in, const int* in_sizes, int n_in,
                              void* d_out, int out_size, void* d_ws, size_t ws_size,
                              hipStream_t stream) {
    const float* feat = (const float*)d_in[0];   // (32,32,32,128)
    const float* cent = (const float*)d_in[1];   // (32,64,128)
    float* out = (float*)d_out;                  // (32,8192)

    char* ws = (char*)d_ws;
    const size_t partial_bytes = (size_t)NB * SPLIT * 64 * 128 * sizeof(float); // 8 MB
    const size_t cws_bytes     = (size_t)NB * 4096 * sizeof(ushort4);           // 1 MB
    const size_t c2_bytes      = (size_t)NB * 64 * sizeof(float);               // 8 KB
    const size_t ssum_bytes    = (size_t)NB * SPLIT * 64 * sizeof(float);       // 64 KB

    float*        partial = (float*)ws;
    ushort4*      cwsp    = (ushort4*)(ws + partial_bytes);
    float*        c2G     = (float*)(ws + partial_bytes + cws_bytes);
    float*        ssumG   = (float*)(ws + partial_bytes + cws_bytes + c2_bytes);
    float*        sqG     = (float*)(ws + partial_bytes + cws_bytes + c2_bytes + ssum_bytes);
    unsigned int* ctr     = (unsigned int*)(ws + partial_bytes + cws_bytes + c2_bytes + ssum_bytes + 256);

    netvlad_prep  <<<256, 256, 0, stream>>>(cent, cwsp, c2G, sqG, ctr);
    netvlad_main  <<<NB * SPLIT, 256, 0, stream>>>(feat, cwsp, c2G, partial, ssumG);
    netvlad_finish<<<256, 256, 0, stream>>>(partial, cent, ssumG, sqG, ctr, out);
}

// Round 10
// 83.795 us; speedup vs baseline: 1.2090x; 1.0911x over previous
//
#include <hip/hip_runtime.h>
#include <hip/hip_bf16.h>

// NetVLAD MI355X v9: r3 topology (512-block main, 2-blocks/CU lesson; separate
// reduce+norm, NO spin barrier). One lever vs r3/v5: phase-1 B-operands read
// directly from L2-resident global hi/lo center images (prep emits plain
// row-major bf16) -> center LDS staging gone, LDS 58.4->25.6 KB, ONE barrier,
// __launch_bounds__(256,3) -> 3 blocks/CU (12 waves/CU, was 8).
// Phase 1: scores = 2*F.C^T - |c|^2, split-bf16 MFMA (3 terms) [verified r2-r9]
// Phase 2: vlad_pos = simT x F_T bf16 MFMA, chunk-XOR swizzles [verified r3-r9]

#define NB    32
#define SPLIT 16

typedef short short8 __attribute__((ext_vector_type(8)));
typedef float f32x4  __attribute__((ext_vector_type(4)));

__device__ __forceinline__ float bf2f(unsigned short u) {
    return __uint_as_float(((unsigned)u) << 16);
}
__device__ __forceinline__ unsigned short f2bf(float f) {
    __hip_bfloat16 h = __float2bfloat16(f);   // RNE
    unsigned short u;
    __builtin_memcpy(&u, &h, 2);
    return u;
}
__device__ __forceinline__ int swz3(int x) { return (x ^ (x >> 3)) & 7; }

// ---- prep: plain row-major bf16 hi/lo center images + c2[b][k] ----
// cgHi/cgLo: bf16[b][64][128] row-major (ushort4 idx: b*2048 + k*32 + d4)
__global__ __launch_bounds__(256)
void netvlad_prep(const float* __restrict__ cent,
                  ushort4* __restrict__ cgHi,
                  ushort4* __restrict__ cgLo,
                  float* __restrict__ c2G) {
    const int tid = threadIdx.x;
    const int bi  = blockIdx.x;      // 256 blocks = 32 b x 8 k-groups
    const int b   = bi >> 3;
    const int kg  = bi & 7;
    const int kk  = tid >> 5;        // 0..7
    const int d4  = tid & 31;
    const int k   = kg * 8 + kk;
    float4 v = ((const float4*)cent)[(size_t)b * 2048 + k * 32 + d4];
    ushort4 h, l;
    h.x = f2bf(v.x); l.x = f2bf(v.x - bf2f(h.x));
    h.y = f2bf(v.y); l.y = f2bf(v.y - bf2f(h.y));
    h.z = f2bf(v.z); l.z = f2bf(v.z - bf2f(h.z));
    h.w = f2bf(v.w); l.w = f2bf(v.w - bf2f(h.w));
    cgHi[(size_t)b * 2048 + k * 32 + d4] = h;
    cgLo[(size_t)b * 2048 + k * 32 + d4] = l;
    float a = v.x * v.x + v.y * v.y + v.z * v.z + v.w * v.w;
    a += __shfl_xor(a, 1);
    a += __shfl_xor(a, 2);
    a += __shfl_xor(a, 4);
    a += __shfl_xor(a, 8);
    a += __shfl_xor(a, 16);
    if (d4 == 0) c2G[b * 64 + k] = a;
}

// LDS map (25,600 B; 3 blocks/CU via launch_bounds VGPR cap):
// [    0,16384) F_T  bf16[128][64], elem: d*64 + (((p>>3) ^ swz3(d))<<3) + (p&7)
// [16384,24576) simT bf16[64][64],  elem: k*64 + (((p>>3) ^ swz3(k))<<3) + (p&7)
// [24576,25600) ssumW f32[4][64]
__global__ __launch_bounds__(256, 3)
void netvlad_main(const float* __restrict__ feat,
                  const short8* __restrict__ cgHi,
                  const short8* __restrict__ cgLo,
                  const float* __restrict__ c2G,
                  float* __restrict__ partial,
                  float* __restrict__ ssumG)
{
    __shared__ __align__(16) char smem[25600];
    unsigned short* FT    = (unsigned short*)smem;
    unsigned short* ST    = (unsigned short*)(smem + 16384);
    float*          ssumW = (float*)(smem + 24576);

    const int tid = threadIdx.x;
    const int bs  = blockIdx.x;
    const int b   = bs >> 4;
    const int n0  = (bs & 15) * 64;

    const float4* feat4 = (const float4*)feat + ((size_t)b * 1024 + n0) * 32;
    const short8* bhp   = cgHi + (size_t)b * 1024;   // 8192 bf16 per batch = 1024 short8
    const short8* blp   = cgLo + (size_t)b * 1024;

    const int w    = tid >> 6;
    const int lane = tid & 63;
    const int lr   = lane & 15;
    const int lg   = lane >> 4;
    const int prow = 16 * w + lr;     // pixel row 0..63

    // ---- c2 from global (L2-hit) ----
    float c2r[4];
    #pragma unroll
    for (int nt = 0; nt < 4; ++nt) c2r[nt] = c2G[b * 64 + nt * 16 + lr];

    // ---- A-frags: global -> regs, split bf16 hi/lo; scatter FT (hi) ----
    short8 ah[4], al[4];
    #pragma unroll
    for (int kt = 0; kt < 4; ++kt) {
        float4 fa = feat4[prow * 32 + kt * 8 + 2 * lg + 0];
        float4 fb = feat4[prow * 32 + kt * 8 + 2 * lg + 1];
        float fv[8] = { fa.x, fa.y, fa.z, fa.w, fb.x, fb.y, fb.z, fb.w };
        #pragma unroll
        for (int j = 0; j < 8; ++j) {
            unsigned short h = f2bf(fv[j]);
            ah[kt][j] = (short)h;
            al[kt][j] = (short)f2bf(fv[j] - bf2f(h));
            int d = kt * 32 + 8 * lg + j;
            FT[d * 64 + ((((prow >> 3) ^ swz3(d))) << 3) + (prow & 7)] = h;
        }
    }

    // ---- phase 1: scores via split-bf16 MFMA, B-frags straight from L2 ----
    f32x4 acc[4];
    #pragma unroll
    for (int nt = 0; nt < 4; ++nt) acc[nt] = (f32x4){0.f, 0.f, 0.f, 0.f};
    #pragma unroll
    for (int kt = 0; kt < 4; ++kt) {
        #pragma unroll
        for (int nt = 0; nt < 4; ++nt) {
            int c  = nt * 16 + lr;
            int ci = c * 16 + kt * 4 + lg;     // short8 index (plain layout)
            short8 bh = bhp[ci];
            short8 bl = blp[ci];
            acc[nt] = __builtin_amdgcn_mfma_f32_16x16x32_bf16(ah[kt], bh, acc[nt], 0, 0, 0);
            acc[nt] = __builtin_amdgcn_mfma_f32_16x16x32_bf16(ah[kt], bl, acc[nt], 0, 0, 0);
            acc[nt] = __builtin_amdgcn_mfma_f32_16x16x32_bf16(al[kt], bh, acc[nt], 0, 0, 0);
        }
    }

    // ---- softmax; write simT bf16; ssum partials ----
    float ssp[4] = {0.f, 0.f, 0.f, 0.f};
    #pragma unroll
    for (int r = 0; r < 4; ++r) {
        float s[4];
        #pragma unroll
        for (int nt = 0; nt < 4; ++nt) s[nt] = 2.f * acc[nt][r] - c2r[nt];
        float m = fmaxf(fmaxf(s[0], s[1]), fmaxf(s[2], s[3]));
        #pragma unroll
        for (int o = 8; o >= 1; o >>= 1) m = fmaxf(m, __shfl_xor(m, o));
        float e[4], t = 0.f;
        #pragma unroll
        for (int nt = 0; nt < 4; ++nt) { e[nt] = __expf(s[nt] - m); t += e[nt]; }
        #pragma unroll
        for (int o = 8; o >= 1; o >>= 1) t += __shfl_xor(t, o);
        float inv = __builtin_amdgcn_rcpf(t);
        int p = 16 * w + 4 * lg + r;
        #pragma unroll
        for (int nt = 0; nt < 4; ++nt) {
            int k = nt * 16 + lr;
            float val = e[nt] * inv;
            ssp[nt] += val;
            ST[k * 64 + ((((p >> 3) ^ swz3(k))) << 3) + (p & 7)] = f2bf(val);
        }
    }
    #pragma unroll
    for (int nt = 0; nt < 4; ++nt) {
        float v = ssp[nt];
        v += __shfl_xor(v, 16);
        v += __shfl_xor(v, 32);
        if (lg == 0) ssumW[w * 64 + nt * 16 + lr] = v;
    }

    __syncthreads();   // the ONE barrier: FT + ST + ssumW all visible

    if (tid < 64)
        ssumG[bs * 64 + tid] = ssumW[tid] + ssumW[64 + tid] + ssumW[128 + tid] + ssumW[192 + tid];

    // ---- phase 2: vlad_pos = simT x F_T via MFMA; wave w owns k-tile w ----
    f32x4 vac[8];
    #pragma unroll
    for (int dt = 0; dt < 8; ++dt) vac[dt] = (f32x4){0.f, 0.f, 0.f, 0.f};
    const int krow = 16 * w + lr;
    #pragma unroll
    for (int ks = 0; ks < 2; ++ks) {
        int cA = (ks * 4 + lg) ^ swz3(krow);
        short8 af = *(const short8*)(ST + krow * 64 + (cA << 3));
        #pragma unroll
        for (int dt = 0; dt < 8; ++dt) {
            int d  = dt * 16 + lr;
            int cB = (ks * 4 + lg) ^ swz3(d);
            short8 bf = *(const short8*)(FT + d * 64 + (cB << 3));
            vac[dt] = __builtin_amdgcn_mfma_f32_16x16x32_bf16(af, bf, vac[dt], 0, 0, 0);
        }
    }

    // ---- write vlad_pos partial ----
    float* outp = partial + (size_t)bs * 8192;
    #pragma unroll
    for (int r = 0; r < 4; ++r) {
        int k = 16 * w + 4 * lg + r;
        #pragma unroll
        for (int dt = 0; dt < 8; ++dt)
            outp[k * 128 + dt * 16 + lr] = vac[dt][r];
    }
}

__global__ __launch_bounds__(256)
void netvlad_reduce(const float* __restrict__ partial,
                    const float* __restrict__ cent,
                    const float* __restrict__ ssumG,
                    float* __restrict__ vlad,
                    float* __restrict__ sqpart) {
    __shared__ float wsum[4];
    int idx = blockIdx.x * 256 + threadIdx.x;   // float4 id over (b, k, d4)
    int b   = idx >> 11;
    int rem = idx & 2047;
    int k   = rem >> 5;
    const float4* p4 = (const float4*)partial;
    float4 a = make_float4(0.f, 0.f, 0.f, 0.f);
    float  ss = 0.f;
    #pragma unroll
    for (int s = 0; s < SPLIT; ++s) {
        float4 v = p4[((size_t)(b * SPLIT + s)) * 2048 + rem];
        a.x += v.x; a.y += v.y; a.z += v.z; a.w += v.w;
        ss += ssumG[(b * SPLIT + s) * 64 + k];
    }
    float4 c4 = ((const float4*)cent)[b * 2048 + rem];
    a.x -= ss * c4.x; a.y -= ss * c4.y; a.z -= ss * c4.z; a.w -= ss * c4.w;
    ((float4*)vlad)[idx] = a;
    float sq = a.x * a.x + a.y * a.y + a.z * a.z + a.w * a.w;
    #pragma unroll
    for (int o = 32; o >= 1; o >>= 1) sq += __shfl_xor(sq, o);
    if ((threadIdx.x & 63) == 0) wsum[threadIdx.x >> 6] = sq;
    __syncthreads();
    if (threadIdx.x == 0) sqpart[blockIdx.x] = wsum[0] + wsum[1] + wsum[2] + wsum[3];
}

__global__ __launch_bounds__(256)
void netvlad_norm(const float* __restrict__ vlad,
                  const float* __restrict__ sqpart,
                  float* __restrict__ out) {
    const float4* sq4 = (const float4*)sqpart;
    float4 v = sq4[threadIdx.x & 63];
    float t = v.x + v.y + v.z + v.w;
    #pragma unroll
    for (int o = 32; o >= 1; o >>= 1) t += __shfl_xor(t, o);
    float inv = __builtin_amdgcn_rcpf(sqrtf(fmaxf(t, 1e-12f)));
    int idx = blockIdx.x * 256 + threadIdx.x;
    float4 x = ((const float4*)vlad)[idx];
    ((float4*)out)[idx] = make_float4(x.x * inv, x.y * inv, x.z * inv, x.w * inv);
}

extern "C" void kernel_launch(void* const* d_in, const int* in_sizes, int n_in,
                              void* d_out, int out_size, void* d_ws, size_t ws_size,
                              hipStream_t stream) {
    const float* feat = (const float*)d_in[0];   // (32,32,32,128)
    const float* cent = (const float*)d_in[1];   // (32,64,128)
    float* out = (float*)d_out;                  // (32,8192)

    char* ws = (char*)d_ws;
    const size_t partial_bytes = (size_t)NB * SPLIT * 64 * 128 * sizeof(float);  // 16 MB
    const size_t cg_bytes      = (size_t)NB * 64 * 128 * sizeof(unsigned short); // 512 KB each
    const size_t c2_bytes      = (size_t)NB * 64 * sizeof(float);                // 8 KB
    const size_t vlad_bytes    = (size_t)NB * 64 * 128 * sizeof(float);          // 1 MB
    const size_t ssum_bytes    = (size_t)NB * SPLIT * 64 * sizeof(float);        // 128 KB

    float*   partial = (float*)ws;
    ushort4* cgHi    = (ushort4*)(ws + partial_bytes);
    ushort4* cgLo    = (ushort4*)(ws + partial_bytes + cg_bytes);
    float*   c2G     = (float*)(ws + partial_bytes + 2 * cg_bytes);
    float*   vlad    = (float*)(ws + partial_bytes + 2 * cg_bytes + c2_bytes);
    float*   ssumG   = (float*)(ws + partial_bytes + 2 * cg_bytes + c2_bytes + vlad_bytes);
    float*   sqpart  = (float*)(ws + partial_bytes + 2 * cg_bytes + c2_bytes + vlad_bytes + ssum_bytes);

    netvlad_prep  <<<256, 256, 0, stream>>>(cent, cgHi, cgLo, c2G);
    netvlad_main  <<<NB * SPLIT, 256, 0, stream>>>(feat, (const short8*)cgHi, (const short8*)cgLo,
                                                   c2G, partial, ssumG);
    netvlad_reduce<<<256, 256, 0, stream>>>(partial, cent, ssumG, vlad, sqpart);
    netvlad_norm  <<<256, 256, 0, stream>>>(vlad, sqpart, out);
}